// Round 12
// baseline (115.438 us; speedup 1.0000x reference)
//
#include <hip/hip_runtime.h>
#include <hip/hip_bf16.h>
#include <math.h>

// S5 SSM layer. B_SZ=16, L=1024, H=256, P=256.
// R22: split at the batch barrier -> 3 dispatches, NO in-kernel cross-block sync:
//   k_prep : W1T/W2T/PW tables
//   k_g1   : GEMM1 (depth-2, wave-private slices) -> LDS X -> scan -> XS + CEND
//   k_g2   : fixed-31 prefix + fixup-in-staging (XS->LDS X) -> GEMM2 -> D*u
// Dispatch boundary provides coherence (plain stores); kernels drain/refill
// independently instead of 512-block lockstep around a barrier.
#define BB     16
#define LSEQ   1024
#define HH     256
#define PP     256
#define LC     32
#define NC     (LSEQ/LC)     // 32
#define NCHUNK (BB*NC)       // 512

// workspace byte offsets
#define OFF_W1T  0u          // [512][256] bf16: row 2p=Re(B_bar[p][.]), 2p+1=Im
#define OFF_W2T  262144u     // [256][512] bf16: row h, k=2p -> 2*C_re, 2p+1 -> -2*C_im
#define OFF_PW   524288u     // [33][256] float2: lambda_bar^t
#define OFF_CEND 655360u     // [512][256] float2 chunk-end local states (1 MB)
#define OFF_XS   2752512u    // [16384][512] bf16 x_local (col 2p=re, 2p+1=im)

typedef __attribute__((ext_vector_type(8))) short short8;
typedef __attribute__((ext_vector_type(4))) float floatx4;

__device__ __forceinline__ float bf2f(unsigned hs) {
    union { unsigned u; float f; } v; v.u = hs << 16; return v.f;
}
__device__ __forceinline__ unsigned short f2bs(float f) {
    __hip_bfloat16 h = __float2bfloat16(f);
    union { __hip_bfloat16 h; unsigned short s; } v; v.h = h; return v.s;
}
__device__ __forceinline__ unsigned packbf(float r, float i) {
    return (unsigned)f2bs(r) | ((unsigned)f2bs(i) << 16);
}
__device__ __forceinline__ void async16(const void* g, void* l) {
    __builtin_amdgcn_global_load_lds(
        (const __attribute__((address_space(1))) unsigned*)g,
        (__attribute__((address_space(3))) unsigned*)l, 16, 0, 0);
}
__device__ __forceinline__ float2 lam_pow(float lr, float li, float dtt) {
    float m = expf(lr * dtt);
    return make_float2(m * cosf(li * dtt), m * sinf(li * dtt));
}

// ---------------- k_prep: W1T/PW (blocks 0..255), W2T (256..511) ----------------
__global__ void k_prep(const float* __restrict__ Bm, const float* __restrict__ Cm,
                       const float* __restrict__ Lr, const float* __restrict__ Li,
                       const float* __restrict__ ls, char* __restrict__ ws) {
    int blk = blockIdx.x, t = threadIdx.x;
    if (blk < 256) {
        if (t < 128) {
            int p = blk;
            float lr = Lr[p], li = Li[p];
            float dt = expf(ls[p]);
            float2 lam = lam_pow(lr, li, dt);
            float den = lr * lr + li * li;
            float nr = lam.x - 1.0f, ni = lam.y;
            float cr = (nr * lr + ni * li) / den;    // (lam_bar-1)/Lambda
            float ci = (ni * lr - nr * li) / den;
            float4 bv = *(const float4*)(Bm + (size_t)p * 512 + 4 * t);
            unsigned* w1u = (unsigned*)(ws + OFF_W1T);
            w1u[(2 * p) * 128 + t]     = packbf(cr * bv.x - ci * bv.y, cr * bv.z - ci * bv.w);
            w1u[(2 * p + 1) * 128 + t] = packbf(cr * bv.y + ci * bv.x, cr * bv.w + ci * bv.z);
            if (t <= 32)
                ((float2*)(ws + OFF_PW))[t * 256 + p] = lam_pow(lr, li, dt * (float)t);
        }
    } else {
        int h = blk - 256, p = t;
        float c_r = Cm[(h * PP + p) * 2 + 0];
        float c_i = Cm[(h * PP + p) * 2 + 1];
        ((unsigned*)(ws + OFF_W2T))[h * 256 + p] = packbf(2.0f * c_r, -2.0f * c_i);
    }
}

// LDS maps:
//   k_g1 (81920 B, 2 blocks/CU): A @0 [32][512B] bf16 XOR-swizzled;
//        B1 @16384 2 bufs x 32768 ([8 waves][64 rows][64 B], chunk-swizzled);
//        X @0 [32][520] bf16 overlays A+B1buf0 after GEMM1.
//   k_g2 (68096 B, 2 blocks/CU): X @0 (33280) + carrs @33280 (2 KB) +
//        B2 @35328 2 bufs x 16384 ([8 waves][32 rows][64 B], chunk-swizzled).
#define XSTRS 520
#define XSTRD 260
#define CARR_OFF 33280
#define B1_OFF  16384
#define B2_OFF  35328

// ---------------- k_g1: GEMM1 + local scan -> XS + CEND -------------------------
__global__ __launch_bounds__(512, 4) void k_g1(
        const float* __restrict__ u, const float* __restrict__ Lr,
        const float* __restrict__ Li, const float* __restrict__ ls,
        char* __restrict__ ws) {
    extern __shared__ char smem[];
    const int tid = threadIdx.x, bc = blockIdx.x;
    const int wave = tid >> 6, lane = tid & 63;
    const int q = lane >> 4, rr = lane & 15;
    const int m0 = bc * LC;
    const int fs = (lane >> 3) & 3;          // staging swizzle = (R>>1)&3 for own slot
    const int fr = (rr >> 1) & 3;            // read swizzle    = (R>>1)&3 for own row

    // ---- GEMM1 panel-0 DMA first (wave-private slice; flies under u-load/pack) --
    const char* W1 = (const char*)(ws + OFF_W1T);
    {
        char* dst = smem + B1_OFF + wave * 4096;
        #pragma unroll
        for (int i = 0; i < 4; ++i) {
            int n = i * 64 + lane;                       // slot in own 4 KB slice
            int R = wave * 64 + (n >> 2);                // global B-row
            async16(W1 + (size_t)R * 512 + (((n & 3) ^ fs) << 4), dst + n * 16);
        }
    }

    // ---- u tile preload + pack -> bf16 into swizzled LDS A ----------------------
    const int arow = tid >> 4, acol = (tid & 15) * 16;   // 16 f32 elems/thread
    {
        float4 uv[4];
        const float* up = u + (size_t)(m0 + arow) * 256 + acol;
        #pragma unroll
        for (int i = 0; i < 4; ++i) uv[i] = *(const float4*)(up + 4 * i);
        unsigned pk[8];
        #pragma unroll
        for (int i = 0; i < 4; ++i) {
            pk[2 * i]     = packbf(uv[i].x, uv[i].y);
            pk[2 * i + 1] = packbf(uv[i].z, uv[i].w);
        }
        const int kb = acol * 2;                   // k-byte base (32 B/thread)
        const int msk = (arow & 7) << 4;
        char* A = smem;
        *(uint4*)(A + arow * 512 + (kb ^ msk))        = make_uint4(pk[0], pk[1], pk[2], pk[3]);
        *(uint4*)(A + arow * 512 + ((kb + 16) ^ msk)) = make_uint4(pk[4], pk[5], pk[6], pk[7]);
    }

    // ---- GEMM1 panel-1 DMA (own slice; target buffer is wave-private) -----------
    {
        char* dst = smem + B1_OFF + 32768 + wave * 4096;
        const char* src = W1 + 64;
        #pragma unroll
        for (int i = 0; i < 4; ++i) {
            int n = i * 64 + lane;
            int R = wave * 64 + (n >> 2);
            async16(src + (size_t)R * 512 + (((n & 3) ^ fs) << 4), dst + n * 16);
        }
    }
    __syncthreads();                           // A visible to all waves

    // ---------------- GEMM1 (BM=32, BN=512, K=256), 8 panels, depth-2 ------------
    {
        const char* A = smem;
        const int amask = (rr & 7) << 4;
        floatx4 acc[2][4];
        #pragma unroll
        for (int i = 0; i < 2; ++i)
            #pragma unroll
            for (int j = 0; j < 4; ++j) acc[i][j] = (floatx4)0.0f;

        #pragma unroll
        for (int t = 0; t < 8; ++t) {
            if (t < 7) { asm volatile("s_waitcnt vmcnt(4)" ::: "memory"); }
            else       { asm volatile("s_waitcnt vmcnt(0)" ::: "memory"); }
            const char* bb = smem + B1_OFF + (t & 1) * 32768 + wave * 4096;
            const int kbA = t * 64 + q * 16;
            short8 a0 = *(const short8*)(A + rr * 512 + (kbA ^ amask));
            short8 a1 = *(const short8*)(A + (16 + rr) * 512 + (kbA ^ amask));
            short8 bfr[4];
            #pragma unroll
            for (int j = 0; j < 4; ++j)
                bfr[j] = *(const short8*)(bb + (j * 16 + rr) * 64 + ((q ^ fr) << 4));
            asm volatile("s_waitcnt lgkmcnt(0)" ::: "memory");   // reads in regs
            __builtin_amdgcn_sched_barrier(0);
            if (t < 6) {    // issue panel t+2 into buf (t&1), just freed
                char* dst = smem + B1_OFF + (t & 1) * 32768 + wave * 4096;
                const char* src = W1 + (t + 2) * 64;
                #pragma unroll
                for (int i = 0; i < 4; ++i) {
                    int n = i * 64 + lane;
                    int R = wave * 64 + (n >> 2);
                    async16(src + (size_t)R * 512 + (((n & 3) ^ fs) << 4), dst + n * 16);
                }
            }
            #pragma unroll
            for (int j = 0; j < 4; ++j) {
                acc[0][j] = __builtin_amdgcn_mfma_f32_16x16x32_bf16(a0, bfr[j], acc[0][j], 0, 0, 0);
                acc[1][j] = __builtin_amdgcn_mfma_f32_16x16x32_bf16(a1, bfr[j], acc[1][j], 0, 0, 0);
            }
        }
        __syncthreads();                       // all waves done with A/B1
        // dump Bu tile (32 x 512) into padded LDS X (overwrites A + B1 head)
        unsigned short* X = (unsigned short*)smem;
        #pragma unroll
        for (int i = 0; i < 2; ++i)
            #pragma unroll
            for (int j = 0; j < 4; ++j)
                #pragma unroll
                for (int r0 = 0; r0 < 4; ++r0)
                    X[(i * 16 + q * 4 + r0) * XSTRS + wave * 64 + j * 16 + rr] =
                        f2bs(acc[i][j][r0]);
        __syncthreads();
    }

    // ---------------- local scan (waves 0-3) -> XS + CEND (plain stores) ---------
    if (tid < 256) {
        const int pq = tid;
        const float2 lam = lam_pow(Lr[pq], Li[pq], expf(ls[pq]));
        unsigned* X32 = (unsigned*)smem;
        unsigned* xs32 = (unsigned*)(ws + OFF_XS);
        float xr = 0.0f, xi = 0.0f;
        #pragma unroll
        for (int j = 0; j < LC; ++j) {
            unsigned cv = X32[j * XSTRD + pq];
            float br = bf2f(cv & 0xffffu), bi = bf2f(cv >> 16);
            float nr = fmaf(lam.x, xr, fmaf(-lam.y, xi, br));
            float ni = fmaf(lam.x, xi, fmaf(lam.y, xr, bi));
            xr = nr; xi = ni;
            xs32[(size_t)(m0 + j) * 256 + pq] = packbf(xr, xi);  // coalesced per row
        }
        ((float2*)(ws + OFF_CEND))[(size_t)bc * 256 + pq] = make_float2(xr, xi);
    }
}

// ---------------- k_g2: prefix + fixup-in-staging + GEMM2 + D*u -----------------
__global__ __launch_bounds__(512, 4) void k_g2(
        const char* __restrict__ ws_c, const float* __restrict__ D,
        const float* __restrict__ u, float* __restrict__ out,
        const float* __restrict__ Lr, const float* __restrict__ Li,
        const float* __restrict__ ls) {
    extern __shared__ char smem[];
    const int tid = threadIdx.x, bc = blockIdx.x;
    const int wave = tid >> 6, lane = tid & 63;
    const int q = lane >> 4, rr = lane & 15;
    const int m0 = bc * LC;
    const int fs = (lane >> 3) & 3;
    const int fr = (rr >> 1) & 3;
    const char* W2 = (const char*)(ws_c + OFF_W2T);
    const unsigned* xs32 = (const unsigned*)(ws_c + OFF_XS);
    char* B2 = smem + B2_OFF;

    // ---- prestage GEMM2 panels 0,1 (cooperative; flies under prefix+fixup) ------
    {
        const int f0 = (tid >> 3) & 3;
        #pragma unroll
        for (int pan = 0; pan < 2; ++pan)
            #pragma unroll
            for (int i = 0; i < 2; ++i) {
                int c = i * 512 + tid;             // linear slot 0..1023
                int R = c >> 2;                    // global B-row 0..255
                async16(W2 + (size_t)R * 1024 + pan * 64 + (((c & 3) ^ f0) << 4),
                        B2 + pan * 16384 + c * 16);
            }
    }

    // ---- XS row loads to registers (fly under the prefix) -----------------------
    const int row = tid >> 4, qd = tid & 15;       // 16 threads/row, 16 pairs each
    const int grow = m0 + row;
    uint4 xv0 = *(const uint4*)(xs32 + (size_t)grow * 256 + qd * 16);
    uint4 xv1 = *(const uint4*)(xs32 + (size_t)grow * 256 + qd * 16 + 4);
    uint4 xv2 = *(const uint4*)(xs32 + (size_t)grow * 256 + qd * 16 + 8);
    uint4 xv3 = *(const uint4*)(xs32 + (size_t)grow * 256 + qd * 16 + 12);

    // ---------------- per-block carry via fixed-31 predicated prefix -------------
    float2* carrs = (float2*)(smem + CARR_OFF);
    if (tid < 256) {
        const int p = tid;
        const int c = bc & (NC - 1);
        const int b0 = bc & ~(NC - 1);
        const float2* cend = (const float2*)(ws_c + OFF_CEND);
        const float2 g = lam_pow(Lr[p], Li[p], expf(ls[p]) * (float)LC);
        float sr = 0.0f, si = 0.0f;
        float gpr = 1.0f, gpi = 0.0f;
        #pragma unroll
        for (int k = 0; k < NC - 1; ++k) {
            int idx = c - 1 - k; idx = idx < 0 ? 0 : idx;
            float2 e = cend[(size_t)(b0 + idx) * 256 + p];
            float er = (k < c) ? e.x : 0.0f;
            float ei = (k < c) ? e.y : 0.0f;
            sr = fmaf(gpr, er, fmaf(-gpi, ei, sr));
            si = fmaf(gpr, ei, fmaf(gpi, er, si));
            float t2 = gpr * g.x - gpi * g.y;
            gpi = gpr * g.y + gpi * g.x; gpr = t2;
        }
        carrs[p] = make_float2(sr, si);
    }
    __syncthreads();

    // ---------------- fixup while staging: X = XS + pw*carry -> LDS --------------
    {
        unsigned* X32 = (unsigned*)smem;
        const float2* pw = (const float2*)(ws_c + OFF_PW);
        const float2* pwr = pw + (size_t)(row + 1) * 256 + qd * 16;
        const float2* cap = carrs + qd * 16;
        unsigned xv[16] = {xv0.x, xv0.y, xv0.z, xv0.w, xv1.x, xv1.y, xv1.z, xv1.w,
                           xv2.x, xv2.y, xv2.z, xv2.w, xv3.x, xv3.y, xv3.z, xv3.w};
        unsigned o[16];
        #pragma unroll
        for (int e = 0; e < 16; ++e) {
            float2 pwv = pwr[e];
            float2 cav = cap[e];
            float fr2 = pwv.x * cav.x - pwv.y * cav.y;
            float fi2 = pwv.x * cav.y + pwv.y * cav.x;
            o[e] = packbf(bf2f(xv[e] & 0xffffu) + fr2, bf2f(xv[e] >> 16) + fi2);
        }
        unsigned* dst = X32 + row * XSTRD + qd * 16;
        *(uint4*)(dst)      = make_uint4(o[0], o[1], o[2], o[3]);
        *(uint4*)(dst + 4)  = make_uint4(o[4], o[5], o[6], o[7]);
        *(uint4*)(dst + 8)  = make_uint4(o[8], o[9], o[10], o[11]);
        *(uint4*)(dst + 12) = make_uint4(o[12], o[13], o[14], o[15]);
    }
    asm volatile("s_waitcnt vmcnt(0)" ::: "memory");   // own prestage DMAs landed
    __syncthreads();                                   // X + panels 0,1 visible

    // ---------------- GEMM2 (BM=32, BN=256, K=512), 16 panels, depth-2 -----------
    {
        const char* Xb = (const char*)smem;
        floatx4 acc[2][2];
        #pragma unroll
        for (int i = 0; i < 2; ++i)
            #pragma unroll
            for (int j = 0; j < 2; ++j) acc[i][j] = (floatx4)0.0f;

        #pragma unroll
        for (int t = 0; t < 16; ++t) {
            if (t < 15) { asm volatile("s_waitcnt vmcnt(2)" ::: "memory"); }
            else        { asm volatile("s_waitcnt vmcnt(0)" ::: "memory"); }
            const char* bbuf = smem + B2_OFF + (t & 1) * 16384 + wave * 2048;
            const int kbA = t * 64 + q * 16;
            short8 a0 = *(const short8*)(Xb + rr * (XSTRS * 2) + kbA);
            short8 a1 = *(const short8*)(Xb + (16 + rr) * (XSTRS * 2) + kbA);
            short8 bfr[2];
            #pragma unroll
            for (int j = 0; j < 2; ++j)
                bfr[j] = *(const short8*)(bbuf + (j * 16 + rr) * 64 + ((q ^ fr) << 4));
            asm volatile("s_waitcnt lgkmcnt(0)" ::: "memory");   // reads in regs
            __builtin_amdgcn_sched_barrier(0);
            if (t < 14) {   // issue panel t+2 into buf (t&1), just freed
                char* dst = smem + B2_OFF + (t & 1) * 16384 + wave * 2048;
                const char* src = W2 + (t + 2) * 64;
                #pragma unroll
                for (int i = 0; i < 2; ++i) {
                    int n = i * 64 + lane;
                    int R = wave * 32 + (n >> 2);
                    async16(src + (size_t)R * 1024 + (((n & 3) ^ fs) << 4), dst + n * 16);
                }
            }
            #pragma unroll
            for (int j = 0; j < 2; ++j) {
                acc[0][j] = __builtin_amdgcn_mfma_f32_16x16x32_bf16(a0, bfr[j], acc[0][j], 0, 0, 0);
                acc[1][j] = __builtin_amdgcn_mfma_f32_16x16x32_bf16(a1, bfr[j], acc[1][j], 0, 0, 0);
            }
        }

        #pragma unroll
        for (int i = 0; i < 2; ++i) {
            int mbase = m0 + i * 16 + q * 4;
            #pragma unroll
            for (int j = 0; j < 2; ++j) {
                int col = wave * 32 + j * 16 + rr;
                #pragma unroll
                for (int r0 = 0; r0 < 4; ++r0) {
                    int rw = mbase + r0;
                    size_t gi = (size_t)rw * 256 + col;
                    out[gi] = acc[i][j][r0] + D[col] * u[gi];
                }
            }
        }
    }
}

extern "C" void kernel_launch(void* const* d_in, const int* in_sizes, int n_in,
                              void* d_out, int out_size, void* d_ws, size_t ws_size,
                              hipStream_t stream) {
    const float* u  = (const float*)d_in[0];
    const float* Lr = (const float*)d_in[1];
    const float* Li = (const float*)d_in[2];
    const float* Bm = (const float*)d_in[3];
    const float* Cm = (const float*)d_in[4];
    const float* D  = (const float*)d_in[5];
    const float* ls = (const float*)d_in[6];
    float* out = (float*)d_out;
    char* ws = (char*)d_ws;

    k_prep<<<512, 256, 0, stream>>>(Bm, Cm, Lr, Li, ls, ws);
    k_g1<<<NCHUNK, 512, 81920, stream>>>(u, Lr, Li, ls, ws);
    k_g2<<<NCHUNK, 512, 68096, stream>>>(ws, D, u, out, Lr, Li, ls);
}

// Round 13
// 101.702 us; speedup vs baseline: 1.1351x; 1.1351x over previous
//
#include <hip/hip_runtime.h>
#include <hip/hip_bf16.h>
#include <math.h>

// S5 SSM layer. B_SZ=16, L=1024, H=256, P=256.
// R23: BM=64 (2 chunks/block), 256 blocks = 1 block/CU, LDS 128 KB.
//  - halves per-XCD L2 traffic for W1/W2 staging (32 MB -> 16 MB): the measured
//    GEMM-phase floor across R16/R19/R21/R22 is B-restaging bandwidth.
//  - 3 staging buffers per GEMM -> true depth-2 prefetch (issue into (t+2)%3
//    right after the vmcnt wait; no buffer conflict, no lgkmcnt gating).
//  - scan + prefix use all 512 threads (2 chunks in parallel); batch = 16 blocks.
#define BB     16
#define LSEQ   1024
#define HH     256
#define PP     256
#define LC     32
#define NC     (LSEQ/LC)     // 32
#define NBLK   256           // 2 chunks per block

// workspace byte offsets
#define OFF_W1T  0u          // [512][256] bf16: row 2p=Re(B_bar[p][.]), 2p+1=Im
#define OFF_W2T  262144u     // [256][512] bf16: row h, k=2p -> 2*C_re, 2p+1 -> -2*C_im
#define OFF_PW   524288u     // [33][256] float2: lambda_bar^t
#define OFF_CEND 655360u     // [512][256] float2 chunk-end local states (1 MB)
#define OFF_BAR  2752512u    // batch-barrier area (zeroed by k_prep block 0)

typedef __attribute__((ext_vector_type(8))) short short8;
typedef __attribute__((ext_vector_type(4))) float floatx4;
typedef unsigned long long ull;

__device__ __forceinline__ float bf2f(unsigned hs) {
    union { unsigned u; float f; } v; v.u = hs << 16; return v.f;
}
__device__ __forceinline__ unsigned short f2bs(float f) {
    __hip_bfloat16 h = __float2bfloat16(f);
    union { __hip_bfloat16 h; unsigned short s; } v; v.h = h; return v.s;
}
__device__ __forceinline__ unsigned packbf(float r, float i) {
    return (unsigned)f2bs(r) | ((unsigned)f2bs(i) << 16);
}
__device__ __forceinline__ void async16(const void* g, void* l) {
    __builtin_amdgcn_global_load_lds(
        (const __attribute__((address_space(1))) unsigned*)g,
        (__attribute__((address_space(3))) unsigned*)l, 16, 0, 0);
}
__device__ __forceinline__ float2 lam_pow(float lr, float li, float dtt) {
    float m = expf(lr * dtt);
    return make_float2(m * cosf(li * dtt), m * sinf(li * dtt));
}
__device__ __forceinline__ void cohst64(ull* p, float2 v) {
    ull b; __builtin_memcpy(&b, &v, 8);
    __hip_atomic_store(p, b, __ATOMIC_RELAXED, __HIP_MEMORY_SCOPE_AGENT);
}

// Batch-scope barrier: 16 blocks of one batch (bc>>4). CEND uses sc1 stores
// (coherent at L3); vmcnt(0) drains them (and B2 prestage DMAs) pre-arrival.
__device__ __forceinline__ void batchbar(char* base) {
    asm volatile("s_waitcnt vmcnt(0)" ::: "memory");
    __syncthreads();
    if (threadIdx.x == 0) {
        const unsigned b = blockIdx.x >> 4;
        unsigned* cnt  = (unsigned*)(base + b * 64);
        unsigned* flag = (unsigned*)(base + 2048 + b * 64);
        if (__hip_atomic_fetch_add(cnt, 1u, __ATOMIC_RELAXED,
                                   __HIP_MEMORY_SCOPE_AGENT) == 15u) {
            __hip_atomic_store(flag, 1u, __ATOMIC_RELAXED, __HIP_MEMORY_SCOPE_AGENT);
        } else {
            for (int it = 0; it < (1 << 18); ++it) {   // bounded: no hang
                if (__hip_atomic_load(flag, __ATOMIC_RELAXED, __HIP_MEMORY_SCOPE_AGENT))
                    break;
                __builtin_amdgcn_s_sleep(2);
            }
        }
    }
    __syncthreads();
}

// ---------------- k_prep: W1T/PW (blocks 0..255), W2T (256..511), bar init ------
__global__ void k_prep(const float* __restrict__ Bm, const float* __restrict__ Cm,
                       const float* __restrict__ Lr, const float* __restrict__ Li,
                       const float* __restrict__ ls, char* __restrict__ ws) {
    int blk = blockIdx.x, t = threadIdx.x;
    if (blk < 256) {
        if (t < 128) {
            int p = blk;
            float lr = Lr[p], li = Li[p];
            float dt = expf(ls[p]);
            float2 lam = lam_pow(lr, li, dt);
            float den = lr * lr + li * li;
            float nr = lam.x - 1.0f, ni = lam.y;
            float cr = (nr * lr + ni * li) / den;    // (lam_bar-1)/Lambda
            float ci = (ni * lr - nr * li) / den;
            float4 bv = *(const float4*)(Bm + (size_t)p * 512 + 4 * t);
            unsigned* w1u = (unsigned*)(ws + OFF_W1T);
            w1u[(2 * p) * 128 + t]     = packbf(cr * bv.x - ci * bv.y, cr * bv.z - ci * bv.w);
            w1u[(2 * p + 1) * 128 + t] = packbf(cr * bv.y + ci * bv.x, cr * bv.w + ci * bv.z);
            if (t <= 32)
                ((float2*)(ws + OFF_PW))[t * 256 + p] = lam_pow(lr, li, dt * (float)t);
        }
        if (blk == 0)   // zero batch-barrier area (4 KB)
            ((float4*)(ws + OFF_BAR))[t] = make_float4(0.f, 0.f, 0.f, 0.f);
    } else {
        int h = blk - 256, p = t;
        float c_r = Cm[(h * PP + p) * 2 + 0];
        float c_i = Cm[(h * PP + p) * 2 + 1];
        ((unsigned*)(ws + OFF_W2T))[h * 256 + p] = packbf(2.0f * c_r, -2.0f * c_i);
    }
}

// LDS map (131072 B, 1 block/CU):
//   GEMM1 : A  @0      [64 rows][512 B] bf16, k-byte XOR-swizzled by (row&7)<<4 (32 KB)
//           B1 @32768  3 bufs x 32768 B ([8 waves][64 rows][64 B], chunk-swizzled)
//   later : X  @0      [64][520] bf16 (66560 B)
//           carrs @66560 [2][256] float2 (4 KB)
//           B2 @70656  3 bufs x 16384 B ([8 waves][32 rows][64 B], chunk-swizzled)
#define XSTRS 520
#define XSTRD 260
#define B1_OFF   32768
#define CARR_OFF 66560
#define B2_OFF   70656
#define LDS_SZ   131072

#define MFMA16(a, b, c) __builtin_amdgcn_mfma_f32_16x16x32_bf16((a), (b), (c), 0, 0, 0)

__global__ __launch_bounds__(512, 2) void k_main(
        const float* __restrict__ u, const float* __restrict__ Lr,
        const float* __restrict__ Li, const float* __restrict__ ls,
        const float* __restrict__ D, float* __restrict__ out,
        char* __restrict__ ws) {
    extern __shared__ char smem[];
    const int tid = threadIdx.x, bc = blockIdx.x;       // bc: 0..255, 2 chunks each
    const int wave = tid >> 6, lane = tid & 63;
    const int q = lane >> 4, rr = lane & 15;
    const int m0 = bc * 64;                             // first row of this block
    const int fs = (lane >> 3) & 3;          // staging swizzle = (R>>1)&3 for own slot
    const int fr = (rr >> 1) & 3;            // read swizzle    = (R>>1)&3 for own row
    const char* W1 = (const char*)(ws + OFF_W1T);
    const char* W2 = (const char*)(ws + OFF_W2T);

    // ---- u tile preload (issued FIRST so pack-waits leave B DMAs in flight) -----
    const int arow = tid >> 3, acol = (tid & 7) * 32;   // 64 rows, 32 f32/thread
    float4 uv[8];
    {
        const float* up = u + (size_t)(m0 + arow) * 256 + acol;
        #pragma unroll
        for (int i = 0; i < 8; ++i) uv[i] = *(const float4*)(up + 4 * i);
    }

    // ---- GEMM1 panels 0,1 DMA (wave-private slices; fly under u-pack) -----------
    #pragma unroll
    for (int pan = 0; pan < 2; ++pan) {
        char* dst = smem + B1_OFF + pan * 32768 + wave * 4096;
        const char* src = W1 + pan * 64;
        #pragma unroll
        for (int i = 0; i < 4; ++i) {
            int n = i * 64 + lane;                       // slot in own 4 KB slice
            int R = wave * 64 + (n >> 2);                // global B-row
            async16(src + (size_t)R * 512 + (((n & 3) ^ fs) << 4), dst + n * 16);
        }
    }

    // ---- pack u -> bf16 into swizzled LDS A -------------------------------------
    {
        unsigned pk[16];
        #pragma unroll
        for (int i = 0; i < 8; ++i) {
            pk[2 * i]     = packbf(uv[i].x, uv[i].y);
            pk[2 * i + 1] = packbf(uv[i].z, uv[i].w);
        }
        const int kb = acol * 2;                   // k-byte base (64 B/thread)
        const int msk = (arow & 7) << 4;
        char* A = smem;
        #pragma unroll
        for (int s = 0; s < 4; ++s)
            *(uint4*)(A + arow * 512 + ((kb + 16 * s) ^ msk)) =
                make_uint4(pk[4 * s], pk[4 * s + 1], pk[4 * s + 2], pk[4 * s + 3]);
    }
    __syncthreads();                           // A visible to all waves

    // ---------------- GEMM1 (BM=64, BN=512, K=256), 8 panels, 3-buf depth-2 ------
    {
        const char* A = smem;
        const int amask = (rr & 7) << 4;
        floatx4 acc[4][4];
        #pragma unroll
        for (int i = 0; i < 4; ++i)
            #pragma unroll
            for (int j = 0; j < 4; ++j) acc[i][j] = (floatx4)0.0f;

        #pragma unroll
        for (int t = 0; t < 8; ++t) {
            if (t < 7) { asm volatile("s_waitcnt vmcnt(4)" ::: "memory"); }
            else       { asm volatile("s_waitcnt vmcnt(0)" ::: "memory"); }
            if (t < 6) {    // issue panel t+2 into buf (t+2)%3 (no conflict with t)
                char* dst = smem + B1_OFF + ((t + 2) % 3) * 32768 + wave * 4096;
                const char* src = W1 + (t + 2) * 64;
                #pragma unroll
                for (int i = 0; i < 4; ++i) {
                    int n = i * 64 + lane;
                    int R = wave * 64 + (n >> 2);
                    async16(src + (size_t)R * 512 + (((n & 3) ^ fs) << 4), dst + n * 16);
                }
            }
            const char* bb = smem + B1_OFF + (t % 3) * 32768 + wave * 4096;
            const int kbA = t * 64 + q * 16;
            short8 a[4], bfr[4];
            #pragma unroll
            for (int i = 0; i < 4; ++i)
                a[i] = *(const short8*)(A + (i * 16 + rr) * 512 + (kbA ^ amask));
            #pragma unroll
            for (int j = 0; j < 4; ++j)
                bfr[j] = *(const short8*)(bb + (j * 16 + rr) * 64 + ((q ^ fr) << 4));
            #pragma unroll
            for (int i = 0; i < 4; ++i)
                #pragma unroll
                for (int j = 0; j < 4; ++j)
                    acc[i][j] = MFMA16(a[i], bfr[j], acc[i][j]);
        }
        __syncthreads();                       // all waves done with A/B1
        // dump Bu tile (64 x 512) into padded LDS X (overlays A + B1 head)
        unsigned short* X = (unsigned short*)smem;
        #pragma unroll
        for (int i = 0; i < 4; ++i)
            #pragma unroll
            for (int j = 0; j < 4; ++j)
                #pragma unroll
                for (int r0 = 0; r0 < 4; ++r0)
                    X[(i * 16 + q * 4 + r0) * XSTRS + wave * 64 + j * 16 + rr] =
                        f2bs(acc[i][j][r0]);
        __syncthreads();
    }

    // ---- prestage GEMM2 panels 0,1 (cooperative; fly under scan+prefix) ---------
    {
        char* B2 = smem + B2_OFF;
        const int f0 = (tid >> 3) & 3;
        #pragma unroll
        for (int pan = 0; pan < 2; ++pan)
            #pragma unroll
            for (int i = 0; i < 2; ++i) {
                int c = i * 512 + tid;             // linear slot 0..1023
                int R = c >> 2;                    // global B-row 0..255
                async16(W2 + (size_t)R * 1024 + pan * 64 + (((c & 3) ^ f0) << 4),
                        B2 + pan * 16384 + c * 16);
            }
    }

    // ---------------- local scan: 512 threads = 2 chunks x 256 channels ----------
    {
        const int hf = tid >> 8, pq = tid & 255;
        const int cc = 2 * bc + hf;                // global chunk id
        const float2 lam = lam_pow(Lr[pq], Li[pq], expf(ls[pq]));
        unsigned* X32 = (unsigned*)smem;
        float xr = 0.0f, xi = 0.0f;
        #pragma unroll
        for (int j = 0; j < LC; ++j) {
            unsigned cv = X32[(hf * 32 + j) * XSTRD + pq];
            float br = bf2f(cv & 0xffffu), bi = bf2f(cv >> 16);
            float nr = fmaf(lam.x, xr, fmaf(-lam.y, xi, br));
            float ni = fmaf(lam.x, xi, fmaf(lam.y, xr, bi));
            xr = nr; xi = ni;
            X32[(hf * 32 + j) * XSTRD + pq] = packbf(xr, xi);   // in place
        }
        cohst64((ull*)(ws + OFF_CEND) + (size_t)cc * 256 + pq, make_float2(xr, xi));
    }
    batchbar(ws + OFF_BAR);        // batch CENDs coherent; B2 panels 0,1 landed

    // ---------------- carries: 512 threads = 2 chunks' fixed-31 prefixes ---------
    {
        float2* carrs = (float2*)(smem + CARR_OFF);    // [2][256]
        const int hf = tid >> 8, p = tid & 255;
        const int c = ((bc & 15) << 1) | hf;           // chunk index within batch
        const int b0 = (bc >> 4) << 5;                 // batch's first chunk
        const float2* cend = (const float2*)(ws + OFF_CEND);
        const float2 g = lam_pow(Lr[p], Li[p], expf(ls[p]) * (float)LC);
        float sr = 0.0f, si = 0.0f;
        float gpr = 1.0f, gpi = 0.0f;
        #pragma unroll
        for (int k = 0; k < NC - 1; ++k) {
            int idx = c - 1 - k; idx = idx < 0 ? 0 : idx;
            float2 e = cend[(size_t)(b0 + idx) * 256 + p];
            float er = (k < c) ? e.x : 0.0f;
            float ei = (k < c) ? e.y : 0.0f;
            sr = fmaf(gpr, er, fmaf(-gpi, ei, sr));
            si = fmaf(gpr, ei, fmaf(gpi, er, si));
            float t2 = gpr * g.x - gpi * g.y;
            gpi = gpr * g.y + gpi * g.x; gpr = t2;
        }
        carrs[hf * 256 + p] = make_float2(sr, si);
        __syncthreads();
    }

    // ---------------- fixup X in place (64 rows x 256 pairs) ---------------------
    {
        const float2* carrs = (const float2*)(smem + CARR_OFF);
        unsigned* X32 = (unsigned*)smem;
        const float2* pw = (const float2*)(ws + OFF_PW);
        const int frow = tid >> 3, f8 = tid & 7;       // 8 threads/row, 32 pairs each
        const float2* pwr = pw + (size_t)((frow & 31) + 1) * 256;
        const float2* cap = carrs + (frow >> 5) * 256;
        #pragma unroll 8
        for (int e = 0; e < 32; ++e) {
            int p = f8 + e * 8;
            unsigned cv = X32[frow * XSTRD + p];
            float2 pwv = pwr[p];
            float2 cav = cap[p];
            float fr2 = pwv.x * cav.x - pwv.y * cav.y;
            float fi2 = pwv.x * cav.y + pwv.y * cav.x;
            X32[frow * XSTRD + p] =
                packbf(bf2f(cv & 0xffffu) + fr2, bf2f(cv >> 16) + fi2);
        }
        __syncthreads();
    }

    // ---------------- GEMM2 (BM=64, BN=256, K=512), 16 panels, 3-buf depth-2 -----
    {
        const char* Xb = (const char*)smem;
        floatx4 acc[4][2];
        #pragma unroll
        for (int i = 0; i < 4; ++i)
            #pragma unroll
            for (int j = 0; j < 2; ++j) acc[i][j] = (floatx4)0.0f;

        #pragma unroll
        for (int t = 0; t < 16; ++t) {
            if (t < 15) { asm volatile("s_waitcnt vmcnt(2)" ::: "memory"); }
            else        { asm volatile("s_waitcnt vmcnt(0)" ::: "memory"); }
            if (t < 14) {   // issue panel t+2 into buf (t+2)%3
                char* dst = smem + B2_OFF + ((t + 2) % 3) * 16384 + wave * 2048;
                const char* src = W2 + (t + 2) * 64;
                #pragma unroll
                for (int i = 0; i < 2; ++i) {
                    int n = i * 64 + lane;
                    int R = wave * 32 + (n >> 2);
                    async16(src + (size_t)R * 1024 + (((n & 3) ^ fs) << 4), dst + n * 16);
                }
            }
            const char* bbuf = smem + B2_OFF + (t % 3) * 16384 + wave * 2048;
            const int kbA = t * 64 + q * 16;
            short8 a[4], bfr[2];
            #pragma unroll
            for (int i = 0; i < 4; ++i)
                a[i] = *(const short8*)(Xb + (i * 16 + rr) * (XSTRS * 2) + kbA);
            #pragma unroll
            for (int j = 0; j < 2; ++j)
                bfr[j] = *(const short8*)(bbuf + (j * 16 + rr) * 64 + ((q ^ fr) << 4));
            #pragma unroll
            for (int i = 0; i < 4; ++i)
                #pragma unroll
                for (int j = 0; j < 2; ++j)
                    acc[i][j] = MFMA16(a[i], bfr[j], acc[i][j]);
        }

        #pragma unroll
        for (int i = 0; i < 4; ++i) {
            int mbase = m0 + i * 16 + q * 4;
            #pragma unroll
            for (int j = 0; j < 2; ++j) {
                int col = wave * 32 + j * 16 + rr;
                #pragma unroll
                for (int r0 = 0; r0 < 4; ++r0) {
                    int rw = mbase + r0;
                    size_t gi = (size_t)rw * 256 + col;
                    out[gi] = acc[i][j][r0] + D[col] * u[gi];
                }
            }
        }
    }
}

extern "C" void kernel_launch(void* const* d_in, const int* in_sizes, int n_in,
                              void* d_out, int out_size, void* d_ws, size_t ws_size,
                              hipStream_t stream) {
    const float* u  = (const float*)d_in[0];
    const float* Lr = (const float*)d_in[1];
    const float* Li = (const float*)d_in[2];
    const float* Bm = (const float*)d_in[3];
    const float* Cm = (const float*)d_in[4];
    const float* D  = (const float*)d_in[5];
    const float* ls = (const float*)d_in[6];
    float* out = (float*)d_out;
    char* ws = (char*)d_ws;

    k_prep<<<512, 256, 0, stream>>>(Bm, Cm, Lr, Li, ls, ws);
    k_main<<<NBLK, 512, LDS_SZ, stream>>>(u, Lr, Li, ls, D, out, ws);
}